// Round 1
// baseline (2512.049 us; speedup 1.0000x reference)
//
#include <hip/hip_runtime.h>
#include <cstdint>
#include <cstddef>

// MoE layer, MI355X. Round 1: correctness-first grouped-GEMM (f32 vector ALU).
// T=4096 tokens, D=1024, F=4096, E=8, top-2.
// ws layout: ints [0..8)=counts [8..16)=cursor [16..25)=offsets
//            [32..32+8192)=pair_slot [8224..16416)=tok_list
//            byte 131072: h (bf16, 8192x4096 = 67MB)
//            then y (f32, 8192x1024 = 33.5MB). Total ~101MB of d_ws.

#define D_MODEL 1024
#define D_FF    4096
#define NEXP    8
#define TOKENS  4096
#define SLOTS   8192

static __device__ __forceinline__ unsigned short f2bf(float f) {
  unsigned int u = __float_as_uint(f);
  u += 0x7fffu + ((u >> 16) & 1u);   // round-to-nearest-even
  return (unsigned short)(u >> 16);
}
static __device__ __forceinline__ float bf2f(unsigned short s) {
  return __uint_as_float(((unsigned int)s) << 16);
}

__global__ void init_kernel(int* __restrict__ wsI) {
  const int i = threadIdx.x;
  if (i < 16) wsI[i] = 0;   // counts + cursor
}

__global__ __launch_bounds__(256) void router_kernel(
    const float* __restrict__ x, const float* __restrict__ gw,
    float* __restrict__ out_logits, float* __restrict__ out_idx,
    float* __restrict__ out_w, int* __restrict__ counts)
{
  const int t = blockIdx.x;
  const int tid = threadIdx.x;
  float p[NEXP];
#pragma unroll
  for (int e = 0; e < NEXP; ++e) p[e] = 0.f;
  const float* xr = x + (size_t)t * D_MODEL;
  for (int d = tid; d < D_MODEL; d += 256) {
    const float xv = xr[d];
    const float* g = gw + (size_t)d * NEXP;
#pragma unroll
    for (int e = 0; e < NEXP; ++e) p[e] += xv * g[e];
  }
#pragma unroll
  for (int e = 0; e < NEXP; ++e) {
    for (int s = 32; s > 0; s >>= 1) p[e] += __shfl_down(p[e], s, 64);
  }
  __shared__ float red[4][NEXP];
  const int lane = tid & 63, wv = tid >> 6;
  if (lane == 0) {
#pragma unroll
    for (int e = 0; e < NEXP; ++e) red[wv][e] = p[e];
  }
  __syncthreads();
  if (tid == 0) {
    float l[NEXP];
#pragma unroll
    for (int e = 0; e < NEXP; ++e)
      l[e] = red[0][e] + red[1][e] + red[2][e] + red[3][e];
    float mx = l[0];
#pragma unroll
    for (int e = 1; e < NEXP; ++e) mx = fmaxf(mx, l[e]);
    float pe[NEXP];
#pragma unroll
    for (int e = 0; e < NEXP; ++e) pe[e] = expf(l[e] - mx);
    // top-2 (ties -> lower index, matching jax.lax.top_k)
    int i0 = 0;
#pragma unroll
    for (int e = 1; e < NEXP; ++e) if (pe[e] > pe[i0]) i0 = e;
    int i1 = (i0 == 0) ? 1 : 0;
#pragma unroll
    for (int e = 0; e < NEXP; ++e)
      if (e != i0 && pe[e] > pe[i1]) i1 = e;
    const float s2 = pe[i0] + pe[i1];
    const float w0 = pe[i0] / s2, w1 = pe[i1] / s2;
#pragma unroll
    for (int e = 0; e < NEXP; ++e) out_logits[(size_t)t * NEXP + e] = l[e];
    out_idx[t * 2 + 0] = (float)i0;
    out_idx[t * 2 + 1] = (float)i1;
    out_w[t * 2 + 0] = w0;
    out_w[t * 2 + 1] = w1;
    atomicAdd(&counts[i0], 1);
    atomicAdd(&counts[i1], 1);
  }
}

__global__ void offsets_kernel(int* __restrict__ wsI) {
  if (threadIdx.x == 0) {
    int s = 0;
    for (int e = 0; e < NEXP; ++e) { wsI[16 + e] = s; s += wsI[e]; }
    wsI[16 + NEXP] = s;
  }
}

__global__ void scatter_kernel(const float* __restrict__ out_idx,
                               int* __restrict__ cursor,
                               const int* __restrict__ offsets,
                               int* __restrict__ pair_slot,
                               int* __restrict__ tok_list)
{
  const int p = blockIdx.x * 256 + threadIdx.x;
  if (p >= SLOTS) return;
  const int e = (int)out_idx[p];
  const int slot = atomicAdd(&cursor[e], 1);
  const int pos = offsets[e] + slot;
  tok_list[pos] = p >> 1;
  pair_slot[p] = pos;
}

// GEMM1: h[off+r, :] = relu(x[tok_list[off+r], :] @ w1[e] + b1[e]);  K=1024, N=4096
__global__ __launch_bounds__(256) void gemm1_kernel(
    const float* __restrict__ x, const float* __restrict__ w1,
    const float* __restrict__ b1, const int* __restrict__ tok_list,
    const int* __restrict__ offsets, unsigned short* __restrict__ h)
{
  const int e = blockIdx.z;
  const int off = offsets[e];
  const int M = offsets[e + 1] - off;
  const int row0 = blockIdx.y * 128;
  if (row0 >= M) return;
  const int col0 = blockIdx.x * 128;
  const int tid = threadIdx.x;

  __shared__ float As[16][132];
  __shared__ float Bs[16][128];

  const int k4 = (tid & 3) * 4;
  const int arow = tid >> 2;           // 0..63
  int tokA[2];
#pragma unroll
  for (int i = 0; i < 2; ++i) {
    const int r = row0 + arow + i * 64;
    tokA[i] = (r < M) ? tok_list[off + r] : -1;
  }
  const int bn = (tid & 31) * 4;
  const int bk = tid >> 5;             // 0..7
  const float* w1e = w1 + (size_t)e * D_MODEL * D_FF;

  float acc[2][2][4][4];
#pragma unroll
  for (int a = 0; a < 2; ++a)
#pragma unroll
    for (int b = 0; b < 2; ++b)
#pragma unroll
      for (int i = 0; i < 4; ++i)
#pragma unroll
        for (int j = 0; j < 4; ++j) acc[a][b][i][j] = 0.f;

  const int tx = tid & 15, ty = tid >> 4;

  for (int kk = 0; kk < D_MODEL; kk += 16) {
#pragma unroll
    for (int i = 0; i < 2; ++i) {
      float4 av = make_float4(0.f, 0.f, 0.f, 0.f);
      if (tokA[i] >= 0)
        av = *(const float4*)(x + (size_t)tokA[i] * D_MODEL + kk + k4);
      As[k4 + 0][arow + i * 64] = av.x;
      As[k4 + 1][arow + i * 64] = av.y;
      As[k4 + 2][arow + i * 64] = av.z;
      As[k4 + 3][arow + i * 64] = av.w;
    }
#pragma unroll
    for (int i = 0; i < 2; ++i) {
      const float4 bv =
          *(const float4*)(w1e + (size_t)(kk + bk + i * 8) * D_FF + col0 + bn);
      *(float4*)&Bs[bk + i * 8][bn] = bv;
    }
    __syncthreads();
#pragma unroll
    for (int k = 0; k < 16; ++k) {
      float a0[4], a1[4], b0[4], b1v[4];
      *(float4*)a0 = *(const float4*)&As[k][ty * 4];
      *(float4*)a1 = *(const float4*)&As[k][64 + ty * 4];
      *(float4*)b0 = *(const float4*)&Bs[k][tx * 4];
      *(float4*)b1v = *(const float4*)&Bs[k][64 + tx * 4];
#pragma unroll
      for (int i = 0; i < 4; ++i) {
#pragma unroll
        for (int j = 0; j < 4; ++j) {
          acc[0][0][i][j] += a0[i] * b0[j];
          acc[0][1][i][j] += a0[i] * b1v[j];
          acc[1][0][i][j] += a1[i] * b0[j];
          acc[1][1][i][j] += a1[i] * b1v[j];
        }
      }
    }
    __syncthreads();
  }
#pragma unroll
  for (int im = 0; im < 2; ++im) {
#pragma unroll
    for (int i = 0; i < 4; ++i) {
      const int r = row0 + im * 64 + ty * 4 + i;
      if (r >= M) continue;
      const size_t hrow = (size_t)(off + r) * D_FF;
#pragma unroll
      for (int jn = 0; jn < 2; ++jn) {
        const int n = col0 + jn * 64 + tx * 4;
        const float4 bias = *(const float4*)(b1 + (size_t)e * D_FF + n);
        ushort4 pk;
        pk.x = f2bf(fmaxf(acc[im][jn][i][0] + bias.x, 0.f));
        pk.y = f2bf(fmaxf(acc[im][jn][i][1] + bias.y, 0.f));
        pk.z = f2bf(fmaxf(acc[im][jn][i][2] + bias.z, 0.f));
        pk.w = f2bf(fmaxf(acc[im][jn][i][3] + bias.w, 0.f));
        *(ushort4*)(h + hrow + n) = pk;
      }
    }
  }
}

// GEMM2: y[off+r, :] = h[off+r, :] @ w2[e] + b2[e];  K=4096, N=1024
__global__ __launch_bounds__(256) void gemm2_kernel(
    const unsigned short* __restrict__ h, const float* __restrict__ w2,
    const float* __restrict__ b2, const int* __restrict__ offsets,
    float* __restrict__ y)
{
  const int e = blockIdx.z;
  const int off = offsets[e];
  const int M = offsets[e + 1] - off;
  const int row0 = blockIdx.y * 128;
  if (row0 >= M) return;
  const int col0 = blockIdx.x * 128;
  const int tid = threadIdx.x;

  __shared__ float As[16][132];
  __shared__ float Bs[16][128];

  const int k4 = (tid & 3) * 4;
  const int arow = tid >> 2;
  bool vA[2];
  size_t aoff[2];
#pragma unroll
  for (int i = 0; i < 2; ++i) {
    const int r = row0 + arow + i * 64;
    vA[i] = (r < M);
    aoff[i] = vA[i] ? (size_t)(off + r) * D_FF : 0;
  }
  const int bn = (tid & 31) * 4;
  const int bk = tid >> 5;
  const float* w2e = w2 + (size_t)e * D_FF * D_MODEL;

  float acc[2][2][4][4];
#pragma unroll
  for (int a = 0; a < 2; ++a)
#pragma unroll
    for (int b = 0; b < 2; ++b)
#pragma unroll
      for (int i = 0; i < 4; ++i)
#pragma unroll
        for (int j = 0; j < 4; ++j) acc[a][b][i][j] = 0.f;

  const int tx = tid & 15, ty = tid >> 4;

  for (int kk = 0; kk < D_FF; kk += 16) {
#pragma unroll
    for (int i = 0; i < 2; ++i) {
      ushort4 hv = make_ushort4(0, 0, 0, 0);
      if (vA[i]) hv = *(const ushort4*)(h + aoff[i] + kk + k4);
      As[k4 + 0][arow + i * 64] = bf2f(hv.x);
      As[k4 + 1][arow + i * 64] = bf2f(hv.y);
      As[k4 + 2][arow + i * 64] = bf2f(hv.z);
      As[k4 + 3][arow + i * 64] = bf2f(hv.w);
    }
#pragma unroll
    for (int i = 0; i < 2; ++i) {
      const float4 bv =
          *(const float4*)(w2e + (size_t)(kk + bk + i * 8) * D_MODEL + col0 + bn);
      *(float4*)&Bs[bk + i * 8][bn] = bv;
    }
    __syncthreads();
#pragma unroll
    for (int k = 0; k < 16; ++k) {
      float a0[4], a1[4], b0[4], b1v[4];
      *(float4*)a0 = *(const float4*)&As[k][ty * 4];
      *(float4*)a1 = *(const float4*)&As[k][64 + ty * 4];
      *(float4*)b0 = *(const float4*)&Bs[k][tx * 4];
      *(float4*)b1v = *(const float4*)&Bs[k][64 + tx * 4];
#pragma unroll
      for (int i = 0; i < 4; ++i) {
#pragma unroll
        for (int j = 0; j < 4; ++j) {
          acc[0][0][i][j] += a0[i] * b0[j];
          acc[0][1][i][j] += a0[i] * b1v[j];
          acc[1][0][i][j] += a1[i] * b0[j];
          acc[1][1][i][j] += a1[i] * b1v[j];
        }
      }
    }
    __syncthreads();
  }
#pragma unroll
  for (int im = 0; im < 2; ++im) {
#pragma unroll
    for (int i = 0; i < 4; ++i) {
      const int r = row0 + im * 64 + ty * 4 + i;
      if (r >= M) continue;
      const size_t yrow = (size_t)(off + r) * D_MODEL;
#pragma unroll
      for (int jn = 0; jn < 2; ++jn) {
        const int n = col0 + jn * 64 + tx * 4;
        const float4 bias = *(const float4*)(b2 + (size_t)e * D_MODEL + n);
        float4 o;
        o.x = acc[im][jn][i][0] + bias.x;
        o.y = acc[im][jn][i][1] + bias.y;
        o.z = acc[im][jn][i][2] + bias.z;
        o.w = acc[im][jn][i][3] + bias.w;
        *(float4*)(y + yrow + n) = o;
      }
    }
  }
}

__global__ __launch_bounds__(256) void combine_kernel(
    const float* __restrict__ y, const int* __restrict__ pair_slot,
    const float* __restrict__ out_w, float* __restrict__ out)
{
  const int gid = blockIdx.x * 256 + threadIdx.x;
  if (gid >= TOKENS * (D_MODEL / 4)) return;
  const int t = gid >> 8;        // 256 float4 per token row
  const int q = gid & 255;
  const float w0 = out_w[t * 2 + 0], w1 = out_w[t * 2 + 1];
  const int p0 = pair_slot[t * 2 + 0], p1 = pair_slot[t * 2 + 1];
  const float4 a = *(const float4*)(y + (size_t)p0 * D_MODEL + q * 4);
  const float4 b = *(const float4*)(y + (size_t)p1 * D_MODEL + q * 4);
  float4 o;
  o.x = w0 * a.x + w1 * b.x;
  o.y = w0 * a.y + w1 * b.y;
  o.z = w0 * a.z + w1 * b.z;
  o.w = w0 * a.w + w1 * b.w;
  *(float4*)(out + (size_t)t * D_MODEL + q * 4) = o;
}

extern "C" void kernel_launch(void* const* d_in, const int* in_sizes, int n_in,
                              void* d_out, int out_size, void* d_ws, size_t ws_size,
                              hipStream_t stream)
{
  (void)in_sizes; (void)n_in; (void)out_size; (void)ws_size;
  const float* x  = (const float*)d_in[0];
  const float* gw = (const float*)d_in[1];
  const float* w1 = (const float*)d_in[2];
  const float* b1 = (const float*)d_in[3];
  const float* w2 = (const float*)d_in[4];
  const float* b2 = (const float*)d_in[5];

  float* out        = (float*)d_out;
  float* out_logits = out + (size_t)TOKENS * D_MODEL;
  float* out_idx    = out_logits + (size_t)TOKENS * NEXP;
  float* out_w      = out_idx + (size_t)TOKENS * 2;

  int* wsI       = (int*)d_ws;
  int* counts    = wsI;
  int* cursor    = wsI + 8;
  int* offsets   = wsI + 16;
  int* pair_slot = wsI + 32;
  int* tok_list  = wsI + 32 + SLOTS;
  unsigned short* h = (unsigned short*)((char*)d_ws + (1 << 17));
  float* y = (float*)((char*)d_ws + (1 << 17) + (size_t)SLOTS * D_FF * 2);

  init_kernel<<<1, 64, 0, stream>>>(wsI);
  router_kernel<<<TOKENS, 256, 0, stream>>>(x, gw, out_logits, out_idx, out_w, counts);
  offsets_kernel<<<1, 64, 0, stream>>>(wsI);
  scatter_kernel<<<SLOTS / 256, 256, 0, stream>>>(out_idx, cursor, offsets, pair_slot, tok_list);
  gemm1_kernel<<<dim3(D_FF / 128, TOKENS / 128, NEXP), 256, 0, stream>>>(
      x, w1, b1, tok_list, offsets, h);
  gemm2_kernel<<<dim3(D_MODEL / 128, TOKENS / 128, NEXP), 256, 0, stream>>>(
      h, w2, b2, offsets, y);
  combine_kernel<<<(TOKENS * D_MODEL / 4) / 256, 256, 0, stream>>>(
      y, pair_slot, out_w, out);
}

// Round 2
// 762.942 us; speedup vs baseline: 3.2926x; 3.2926x over previous
//
#include <hip/hip_runtime.h>
#include <cstdint>
#include <cstddef>

// MoE layer, MI355X. Round 2: bf16 MFMA grouped-GEMM (m97-style structure).
// T=4096 tokens, D=1024, F=4096, E=8, top-2. Padded slots: 9216 (128-aligned per expert).

#define D_MODEL 1024
#define D_FF    4096
#define NEXP    8
#define TOKENS  4096
#define SLOTS   8192
#define SLOTSP  9216   // 8192 + 8*128 headroom, 128-aligned per expert
#define MAXBLK  96

typedef __bf16 bf16x8 __attribute__((ext_vector_type(8)));
typedef float  f32x4  __attribute__((ext_vector_type(4)));

static __device__ __forceinline__ unsigned short f2bf(float f) {
  unsigned int u = __float_as_uint(f);
  u += 0x7fffu + ((u >> 16) & 1u);   // RNE
  return (unsigned short)(u >> 16);
}

static __device__ __forceinline__ void async_ld16(const void* g, void* l) {
  __builtin_amdgcn_global_load_lds(
      (const __attribute__((address_space(1))) void*)g,
      (__attribute__((address_space(3))) void*)l, 16, 0, 0);
}

// ---------------- setup kernels ----------------

__global__ void init_kernel(int* __restrict__ wsI, int* __restrict__ tok_list) {
  const int g = blockIdx.x * 256 + threadIdx.x;
  if (g < 16) wsI[g] = 0;            // counts[8] + cursor[8]
  if (g < SLOTSP) tok_list[g] = -1;
}

__global__ __launch_bounds__(256) void router_kernel(
    const float* __restrict__ x, const float* __restrict__ gw,
    float* __restrict__ out_logits, float* __restrict__ out_idx,
    float* __restrict__ out_w, int* __restrict__ counts)
{
  const int t = blockIdx.x;
  const int tid = threadIdx.x;
  float p[NEXP];
#pragma unroll
  for (int e = 0; e < NEXP; ++e) p[e] = 0.f;
  const float* xr = x + (size_t)t * D_MODEL;
  for (int d = tid; d < D_MODEL; d += 256) {
    const float xv = xr[d];
    const float* g = gw + (size_t)d * NEXP;
#pragma unroll
    for (int e = 0; e < NEXP; ++e) p[e] += xv * g[e];
  }
#pragma unroll
  for (int e = 0; e < NEXP; ++e) {
    for (int s = 32; s > 0; s >>= 1) p[e] += __shfl_down(p[e], s, 64);
  }
  __shared__ float red[4][NEXP];
  const int lane = tid & 63, wv = tid >> 6;
  if (lane == 0) {
#pragma unroll
    for (int e = 0; e < NEXP; ++e) red[wv][e] = p[e];
  }
  __syncthreads();
  if (tid == 0) {
    float l[NEXP];
#pragma unroll
    for (int e = 0; e < NEXP; ++e)
      l[e] = red[0][e] + red[1][e] + red[2][e] + red[3][e];
    float mx = l[0];
#pragma unroll
    for (int e = 1; e < NEXP; ++e) mx = fmaxf(mx, l[e]);
    float pe[NEXP];
#pragma unroll
    for (int e = 0; e < NEXP; ++e) pe[e] = expf(l[e] - mx);
    int i0 = 0;
#pragma unroll
    for (int e = 1; e < NEXP; ++e) if (pe[e] > pe[i0]) i0 = e;
    int i1 = (i0 == 0) ? 1 : 0;
#pragma unroll
    for (int e = 0; e < NEXP; ++e)
      if (e != i0 && pe[e] > pe[i1]) i1 = e;
    const float s2 = pe[i0] + pe[i1];
#pragma unroll
    for (int e = 0; e < NEXP; ++e) out_logits[(size_t)t * NEXP + e] = l[e];
    out_idx[t * 2 + 0] = (float)i0;
    out_idx[t * 2 + 1] = (float)i1;
    out_w[t * 2 + 0] = pe[i0] / s2;
    out_w[t * 2 + 1] = pe[i1] / s2;
    atomicAdd(&counts[i0], 1);
    atomicAdd(&counts[i1], 1);
  }
}

// po[e]=wsI[16+e] (padded offsets), wsI[25]=nblocks, blk_e=wsI[32..], blk_gr0=wsI[128..]
__global__ void offsets_kernel(int* __restrict__ wsI) {
  if (threadIdx.x == 0) {
    int s = 0, nb = 0;
    for (int e = 0; e < NEXP; ++e) {
      wsI[16 + e] = s;
      const int cnt = wsI[e];
      const int nblk = (cnt + 127) >> 7;
      for (int j = 0; j < nblk; ++j) {
        wsI[32 + nb] = e;
        wsI[128 + nb] = s + j * 128;
        ++nb;
      }
      s += nblk << 7;
    }
    wsI[16 + NEXP] = s;
    wsI[25] = nb;
  }
}

__global__ void scatter_kernel(const float* __restrict__ out_idx,
                               int* __restrict__ cursor,
                               const int* __restrict__ po,
                               int* __restrict__ pair_slot,
                               int* __restrict__ tok_list)
{
  const int p = blockIdx.x * 256 + threadIdx.x;
  if (p >= SLOTS) return;
  const int e = (int)out_idx[p];
  const int slot = atomicAdd(&cursor[e], 1);
  const int pos = po[e] + slot;
  tok_list[pos] = p >> 1;
  pair_slot[p] = pos;
}

// gather x rows into slot order, f32 -> bf16
__global__ __launch_bounds__(256) void gather_cvt(
    const float* __restrict__ x, const int* __restrict__ tok_list,
    unsigned short* __restrict__ xg)
{
  const int gid = blockIdx.x * 256 + threadIdx.x;
  const int row = gid >> 7, seg = gid & 127;   // 128 threads/row, 8 elem each
  const int tok = tok_list[row];
  if (tok < 0) return;
  const float* src = x + (size_t)tok * D_MODEL + seg * 8;
  const float4 a = *(const float4*)(src);
  const float4 b = *(const float4*)(src + 4);
  ushort4 lo = make_ushort4(f2bf(a.x), f2bf(a.y), f2bf(a.z), f2bf(a.w));
  ushort4 hi = make_ushort4(f2bf(b.x), f2bf(b.y), f2bf(b.z), f2bf(b.w));
  unsigned short* d = xg + (size_t)row * D_MODEL + seg * 8;
  *(ushort4*)(d) = lo;
  *(ushort4*)(d + 4) = hi;
}

// src [E][K][N] f32 -> dst [E][N][K] bf16, tile 64k x 32n
__global__ __launch_bounds__(256) void transpose_cvt(
    const float* __restrict__ src, unsigned short* __restrict__ dst,
    int K, int N)
{
  const int e = blockIdx.z;
  const int n0 = blockIdx.x * 32;
  const int k0 = blockIdx.y * 64;
  __shared__ float t[64][33];
  const int tx = threadIdx.x & 31, ty = threadIdx.x >> 5;   // ty 0..7
  const float* s = src + (size_t)e * K * N;
#pragma unroll
  for (int i = 0; i < 8; ++i)
    t[ty + i * 8][tx] = s[(size_t)(k0 + ty + i * 8) * N + n0 + tx];
  __syncthreads();
  unsigned short* d = dst + (size_t)e * N * K;
  const int kp = threadIdx.x & 31;   // k-pair index
  const int r = threadIdx.x >> 5;    // 0..7
#pragma unroll
  for (int i = 0; i < 4; ++i) {
    const int n = r + i * 8;
    ushort2 v;
    v.x = f2bf(t[kp * 2 + 0][n]);
    v.y = f2bf(t[kp * 2 + 1][n]);
    *(ushort2*)&d[(size_t)(n0 + n) * K + k0 + kp * 2] = v;
  }
}

// ---------------- MFMA grouped GEMM ----------------
// C[row, :] = act(A[row, :] @ Bt[e]^T + bias[e]);  A: [SLOTSP][K] bf16 (slot-ordered),
// Bt: [E][N][K] bf16 (N-major), C: [SLOTSP][N]. RELU=1 -> bf16-out relu, else f32-out.
template <int RELU>
__global__ __launch_bounds__(256) void gemm_mfma(
    const unsigned short* __restrict__ A, const unsigned short* __restrict__ Bt,
    const float* __restrict__ bias, void* __restrict__ Cout,
    const int* __restrict__ wsI, int K, int N)
{
  if ((int)blockIdx.y >= wsI[25]) return;
  const int e = wsI[32 + blockIdx.y];
  const int gr0 = wsI[128 + blockIdx.y];
  const int col0 = blockIdx.x * 128;

  __shared__ unsigned short ldsA[128 * 32];
  __shared__ unsigned short ldsB[128 * 32];

  const int tid = threadIdx.x;
  const int lane = tid & 63;
  const int w = tid >> 6;
  const int wr = w >> 1, wc = w & 1;
  const int m15 = lane & 15, q = lane >> 4;

  f32x4 zero = {0.f, 0.f, 0.f, 0.f};
  f32x4 acc[4][4];
#pragma unroll
  for (int mt = 0; mt < 4; ++mt)
#pragma unroll
    for (int nt = 0; nt < 4; ++nt) acc[mt][nt] = zero;

  const int r4 = tid >> 2;            // 0..63 (row in 64-row group)
  const int c8 = (tid & 3) * 8;       // k offset 0/8/16/24
  const unsigned short* Ab = A + (size_t)gr0 * K + (size_t)r4 * K + c8;
  const unsigned short* Bb = Bt + (size_t)e * N * K + (size_t)(col0 + r4) * K + c8;

  for (int kk = 0; kk < K; kk += 32) {
    async_ld16(Ab + kk, &ldsA[tid * 8]);
    async_ld16(Ab + (size_t)64 * K + kk, &ldsA[2048 + tid * 8]);
    async_ld16(Bb + kk, &ldsB[tid * 8]);
    async_ld16(Bb + (size_t)64 * K + kk, &ldsB[2048 + tid * 8]);
    __syncthreads();
    bf16x8 af[4], bf[4];
#pragma unroll
    for (int mt = 0; mt < 4; ++mt)
      af[mt] = *(const bf16x8*)&ldsA[(wr * 64 + mt * 16 + m15) * 32 + q * 8];
#pragma unroll
    for (int nt = 0; nt < 4; ++nt)
      bf[nt] = *(const bf16x8*)&ldsB[(wc * 64 + nt * 16 + m15) * 32 + q * 8];
#pragma unroll
    for (int mt = 0; mt < 4; ++mt)
#pragma unroll
      for (int nt = 0; nt < 4; ++nt)
        acc[mt][nt] = __builtin_amdgcn_mfma_f32_16x16x32_bf16(
            af[mt], bf[nt], acc[mt][nt], 0, 0, 0);
    __syncthreads();
  }

  // epilogue: C/D layout col=lane&15, row=q*4+i
#pragma unroll
  for (int nt = 0; nt < 4; ++nt) {
    const int c = col0 + wc * 64 + nt * 16 + m15;
    const float bv = bias[(size_t)e * N + c];
#pragma unroll
    for (int mt = 0; mt < 4; ++mt) {
      const size_t rbase = (size_t)(gr0 + wr * 64 + mt * 16 + q * 4);
      if (RELU) {
        unsigned short* Cp = (unsigned short*)Cout;
#pragma unroll
        for (int i = 0; i < 4; ++i)
          Cp[(rbase + i) * N + c] = f2bf(fmaxf(acc[mt][nt][i] + bv, 0.f));
      } else {
        float* Cp = (float*)Cout;
#pragma unroll
        for (int i = 0; i < 4; ++i)
          Cp[(rbase + i) * N + c] = acc[mt][nt][i] + bv;
      }
    }
  }
}

__global__ __launch_bounds__(256) void combine_kernel(
    const float* __restrict__ y, const int* __restrict__ pair_slot,
    const float* __restrict__ out_w, float* __restrict__ out)
{
  const int gid = blockIdx.x * 256 + threadIdx.x;
  if (gid >= TOKENS * (D_MODEL / 4)) return;
  const int t = gid >> 8;
  const int qd = gid & 255;
  const float w0 = out_w[t * 2 + 0], w1 = out_w[t * 2 + 1];
  const int p0 = pair_slot[t * 2 + 0], p1 = pair_slot[t * 2 + 1];
  const float4 a = *(const float4*)(y + (size_t)p0 * D_MODEL + qd * 4);
  const float4 b = *(const float4*)(y + (size_t)p1 * D_MODEL + qd * 4);
  float4 o;
  o.x = w0 * a.x + w1 * b.x;
  o.y = w0 * a.y + w1 * b.y;
  o.z = w0 * a.z + w1 * b.z;
  o.w = w0 * a.w + w1 * b.w;
  *(float4*)(out + (size_t)t * D_MODEL + qd * 4) = o;
}

extern "C" void kernel_launch(void* const* d_in, const int* in_sizes, int n_in,
                              void* d_out, int out_size, void* d_ws, size_t ws_size,
                              hipStream_t stream)
{
  (void)in_sizes; (void)n_in; (void)out_size; (void)ws_size;
  const float* x  = (const float*)d_in[0];
  const float* gw = (const float*)d_in[1];
  const float* w1 = (const float*)d_in[2];
  const float* b1 = (const float*)d_in[3];
  const float* w2 = (const float*)d_in[4];
  const float* b2 = (const float*)d_in[5];

  float* out        = (float*)d_out;
  float* out_logits = out + (size_t)TOKENS * D_MODEL;
  float* out_idx    = out_logits + (size_t)TOKENS * NEXP;
  float* out_w      = out_idx + (size_t)TOKENS * 2;

  int* wsI       = (int*)d_ws;
  int* po        = wsI + 16;
  int* tok_list  = wsI + 512;
  int* pair_slot = wsI + 10240;
  unsigned short* xg  = (unsigned short*)((char*)d_ws + (1 << 17));
  unsigned short* w1t = xg  + (size_t)SLOTSP * D_MODEL;
  unsigned short* w2t = w1t + (size_t)NEXP * D_FF * D_MODEL;
  unsigned short* h   = w2t + (size_t)NEXP * D_MODEL * D_FF;
  float*          y   = (float*)(h + (size_t)SLOTSP * D_FF);

  init_kernel<<<SLOTSP / 256, 256, 0, stream>>>(wsI, tok_list);
  router_kernel<<<TOKENS, 256, 0, stream>>>(x, gw, out_logits, out_idx, out_w, wsI);
  offsets_kernel<<<1, 64, 0, stream>>>(wsI);
  scatter_kernel<<<SLOTS / 256, 256, 0, stream>>>(out_idx, wsI + 8, po, pair_slot, tok_list);
  gather_cvt<<<SLOTSP * 128 / 256, 256, 0, stream>>>(x, tok_list, xg);
  transpose_cvt<<<dim3(D_FF / 32, D_MODEL / 64, NEXP), 256, 0, stream>>>(w1, w1t, D_MODEL, D_FF);
  transpose_cvt<<<dim3(D_MODEL / 32, D_FF / 64, NEXP), 256, 0, stream>>>(w2, w2t, D_FF, D_MODEL);
  gemm_mfma<1><<<dim3(D_FF / 128, 72, 1), 256, 0, stream>>>(
      xg, w1t, b1, (void*)h, wsI, D_MODEL, D_FF);
  gemm_mfma<0><<<dim3(D_MODEL / 128, 72, 1), 256, 0, stream>>>(
      h, w2t, b2, (void*)y, wsI, D_FF, D_MODEL);
  combine_kernel<<<(TOKENS * D_MODEL / 4) / 256, 256, 0, stream>>>(
      y, pair_slot, out_w, out);
}

// Round 3
// 752.784 us; speedup vs baseline: 3.3370x; 1.0135x over previous
//
#include <hip/hip_runtime.h>
#include <cstdint>
#include <cstddef>

// MoE layer, MI355X. Round 3: bf16 MFMA grouped-GEMM + XOR-swizzled LDS
// (bank-conflict-free fragment reads) + tiled weight transpose.
// T=4096 tokens, D=1024, F=4096, E=8, top-2. Padded slots: 9216.

#define D_MODEL 1024
#define D_FF    4096
#define NEXP    8
#define TOKENS  4096
#define SLOTS   8192
#define SLOTSP  9216

typedef __bf16 bf16x8 __attribute__((ext_vector_type(8)));
typedef float  f32x4  __attribute__((ext_vector_type(4)));

static __device__ __forceinline__ unsigned short f2bf(float f) {
  unsigned int u = __float_as_uint(f);
  u += 0x7fffu + ((u >> 16) & 1u);   // RNE
  return (unsigned short)(u >> 16);
}

static __device__ __forceinline__ void async_ld16(const void* g, void* l) {
  __builtin_amdgcn_global_load_lds(
      (const __attribute__((address_space(1))) void*)g,
      (__attribute__((address_space(3))) void*)l, 16, 0, 0);
}

// ---------------- setup kernels ----------------

__global__ void init_kernel(int* __restrict__ wsI, int* __restrict__ tok_list) {
  const int g = blockIdx.x * 256 + threadIdx.x;
  if (g < 16) wsI[g] = 0;            // counts[8] + cursor[8]
  if (g < SLOTSP) tok_list[g] = -1;
}

__global__ __launch_bounds__(256) void router_kernel(
    const float* __restrict__ x, const float* __restrict__ gw,
    float* __restrict__ out_logits, float* __restrict__ out_idx,
    float* __restrict__ out_w, int* __restrict__ counts)
{
  const int t = blockIdx.x;
  const int tid = threadIdx.x;
  float p[NEXP];
#pragma unroll
  for (int e = 0; e < NEXP; ++e) p[e] = 0.f;
  const float* xr = x + (size_t)t * D_MODEL;
  for (int d = tid; d < D_MODEL; d += 256) {
    const float xv = xr[d];
    const float* g = gw + (size_t)d * NEXP;
#pragma unroll
    for (int e = 0; e < NEXP; ++e) p[e] += xv * g[e];
  }
#pragma unroll
  for (int e = 0; e < NEXP; ++e) {
    for (int s = 32; s > 0; s >>= 1) p[e] += __shfl_down(p[e], s, 64);
  }
  __shared__ float red[4][NEXP];
  const int lane = tid & 63, wv = tid >> 6;
  if (lane == 0) {
#pragma unroll
    for (int e = 0; e < NEXP; ++e) red[wv][e] = p[e];
  }
  __syncthreads();
  if (tid == 0) {
    float l[NEXP];
#pragma unroll
    for (int e = 0; e < NEXP; ++e)
      l[e] = red[0][e] + red[1][e] + red[2][e] + red[3][e];
    float mx = l[0];
#pragma unroll
    for (int e = 1; e < NEXP; ++e) mx = fmaxf(mx, l[e]);
    float pe[NEXP];
#pragma unroll
    for (int e = 0; e < NEXP; ++e) pe[e] = expf(l[e] - mx);
    int i0 = 0;
#pragma unroll
    for (int e = 1; e < NEXP; ++e) if (pe[e] > pe[i0]) i0 = e;
    int i1 = (i0 == 0) ? 1 : 0;
#pragma unroll
    for (int e = 0; e < NEXP; ++e)
      if (e != i0 && pe[e] > pe[i1]) i1 = e;
    const float s2 = pe[i0] + pe[i1];
#pragma unroll
    for (int e = 0; e < NEXP; ++e) out_logits[(size_t)t * NEXP + e] = l[e];
    out_idx[t * 2 + 0] = (float)i0;
    out_idx[t * 2 + 1] = (float)i1;
    out_w[t * 2 + 0] = pe[i0] / s2;
    out_w[t * 2 + 1] = pe[i1] / s2;
    atomicAdd(&counts[i0], 1);
    atomicAdd(&counts[i1], 1);
  }
}

// po[e]=wsI[16+e] (padded offsets), wsI[25]=nblocks, blk_e=wsI[32..], blk_gr0=wsI[128..]
__global__ void offsets_kernel(int* __restrict__ wsI) {
  if (threadIdx.x == 0) {
    int s = 0, nb = 0;
    for (int e = 0; e < NEXP; ++e) {
      wsI[16 + e] = s;
      const int cnt = wsI[e];
      const int nblk = (cnt + 127) >> 7;
      for (int j = 0; j < nblk; ++j) {
        wsI[32 + nb] = e;
        wsI[128 + nb] = s + j * 128;
        ++nb;
      }
      s += nblk << 7;
    }
    wsI[16 + NEXP] = s;
    wsI[25] = nb;
  }
}

__global__ void scatter_kernel(const float* __restrict__ out_idx,
                               int* __restrict__ cursor,
                               const int* __restrict__ po,
                               int* __restrict__ pair_slot,
                               int* __restrict__ tok_list)
{
  const int p = blockIdx.x * 256 + threadIdx.x;
  if (p >= SLOTS) return;
  const int e = (int)out_idx[p];
  const int slot = atomicAdd(&cursor[e], 1);
  const int pos = po[e] + slot;
  tok_list[pos] = p >> 1;
  pair_slot[p] = pos;
}

// gather x rows into slot order, f32 -> bf16
__global__ __launch_bounds__(256) void gather_cvt(
    const float* __restrict__ x, const int* __restrict__ tok_list,
    unsigned short* __restrict__ xg)
{
  const int gid = blockIdx.x * 256 + threadIdx.x;
  const int row = gid >> 7, seg = gid & 127;   // 128 threads/row, 8 elem each
  const int tok = tok_list[row];
  if (tok < 0) return;
  const float* src = x + (size_t)tok * D_MODEL + seg * 8;
  const float4 a = *(const float4*)(src);
  const float4 b = *(const float4*)(src + 4);
  ushort4 lo = make_ushort4(f2bf(a.x), f2bf(a.y), f2bf(a.z), f2bf(a.w));
  ushort4 hi = make_ushort4(f2bf(b.x), f2bf(b.y), f2bf(b.z), f2bf(b.w));
  unsigned short* d = xg + (size_t)row * D_MODEL + seg * 8;
  *(ushort4*)(d) = lo;
  *(ushort4*)(d + 4) = hi;
}

// src [E][K][N] f32 -> dst [E][N][K] bf16, 64x64 LDS-tiled
__global__ __launch_bounds__(256) void transpose_cvt(
    const float* __restrict__ src, unsigned short* __restrict__ dst,
    int K, int N)
{
  const int e = blockIdx.z;
  const int n0 = blockIdx.x * 64;
  const int k0 = blockIdx.y * 64;
  __shared__ float t[64][65];
  const int c4 = (threadIdx.x & 15) * 4;
  const int r  = threadIdx.x >> 4;        // 0..15
  const float* s = src + (size_t)e * K * N + (size_t)k0 * N + n0;
#pragma unroll
  for (int i = 0; i < 4; ++i) {
    const float4 v = *(const float4*)(s + (size_t)(r + 16 * i) * N + c4);
    t[r + 16 * i][c4 + 0] = v.x;
    t[r + 16 * i][c4 + 1] = v.y;
    t[r + 16 * i][c4 + 2] = v.z;
    t[r + 16 * i][c4 + 3] = v.w;
  }
  __syncthreads();
  unsigned short* d = dst + (size_t)e * N * K + (size_t)n0 * K + k0;
#pragma unroll
  for (int i = 0; i < 4; ++i) {
    const int n = r + 16 * i;
    ushort4 v;
    v.x = f2bf(t[c4 + 0][n]);
    v.y = f2bf(t[c4 + 1][n]);
    v.z = f2bf(t[c4 + 2][n]);
    v.w = f2bf(t[c4 + 3][n]);
    *(ushort4*)(d + (size_t)n * K + c4) = v;
  }
}

// ---------------- MFMA grouped GEMM ----------------
// C[row, :] = act(A[row, :] @ Bt[e]^T + bias[e]);  A: [SLOTSP][K] bf16 (slot-ordered),
// Bt: [E][N][K] bf16 (N-major), C: [SLOTSP][N]. RELU=1 -> bf16-out relu, else f32-out.
// LDS layout is XOR-swizzled: k-segment ks (16B) of row r lives at slot
// r*4 + (ks ^ ((r>>1)&3)).  Staging keeps global coalescing (each 4-lane group
// fetches a permutation of the same 64B row chunk); fragment ds_read_b128 phases
// then cover all 32 banks exactly 2x (free).
template <int RELU>
__global__ __launch_bounds__(256) void gemm_mfma(
    const unsigned short* __restrict__ A, const unsigned short* __restrict__ Bt,
    const float* __restrict__ bias, void* __restrict__ Cout,
    const int* __restrict__ wsI, int K, int N)
{
  if ((int)blockIdx.y >= wsI[25]) return;
  const int e = wsI[32 + blockIdx.y];
  const int gr0 = wsI[128 + blockIdx.y];
  const int col0 = blockIdx.x * 128;

  __shared__ unsigned short ldsA[128 * 32];
  __shared__ unsigned short ldsB[128 * 32];

  const int tid = threadIdx.x;
  const int lane = tid & 63;
  const int w = tid >> 6;
  const int wr = w >> 1, wc = w & 1;
  const int m15 = lane & 15, q = lane >> 4;

  f32x4 zero = {0.f, 0.f, 0.f, 0.f};
  f32x4 acc[4][4];
#pragma unroll
  for (int mt = 0; mt < 4; ++mt)
#pragma unroll
    for (int nt = 0; nt < 4; ++nt) acc[mt][nt] = zero;

  const int r4 = tid >> 2;                          // 0..63 (row in 64-row group)
  const int ks = (tid & 3) ^ ((tid >> 3) & 3);      // swizzled k-segment
  const int c8 = ks * 8;
  const unsigned short* Ab = A + (size_t)(gr0 + r4) * K + c8;
  const unsigned short* Bb = Bt + (size_t)e * N * K + (size_t)(col0 + r4) * K + c8;

  // fragment LDS offsets (halfs): row*32 + (q ^ ((m15>>1)&3))*8
  const int fswz = (q ^ ((m15 >> 1) & 3)) * 8;

  for (int kk = 0; kk < K; kk += 32) {
    async_ld16(Ab + kk, &ldsA[tid * 8]);
    async_ld16(Ab + (size_t)64 * K + kk, &ldsA[2048 + tid * 8]);
    async_ld16(Bb + kk, &ldsB[tid * 8]);
    async_ld16(Bb + (size_t)64 * K + kk, &ldsB[2048 + tid * 8]);
    __syncthreads();
    bf16x8 af[4], bf[4];
#pragma unroll
    for (int mt = 0; mt < 4; ++mt)
      af[mt] = *(const bf16x8*)&ldsA[(wr * 64 + mt * 16 + m15) * 32 + fswz];
#pragma unroll
    for (int nt = 0; nt < 4; ++nt)
      bf[nt] = *(const bf16x8*)&ldsB[(wc * 64 + nt * 16 + m15) * 32 + fswz];
#pragma unroll
    for (int mt = 0; mt < 4; ++mt)
#pragma unroll
      for (int nt = 0; nt < 4; ++nt)
        acc[mt][nt] = __builtin_amdgcn_mfma_f32_16x16x32_bf16(
            af[mt], bf[nt], acc[mt][nt], 0, 0, 0);
    __syncthreads();
  }

  // epilogue: C/D layout col=lane&15, row=q*4+i
#pragma unroll
  for (int nt = 0; nt < 4; ++nt) {
    const int c = col0 + wc * 64 + nt * 16 + m15;
    const float bv = bias[(size_t)e * N + c];
#pragma unroll
    for (int mt = 0; mt < 4; ++mt) {
      const size_t rbase = (size_t)(gr0 + wr * 64 + mt * 16 + q * 4);
      if (RELU) {
        unsigned short* Cp = (unsigned short*)Cout;
#pragma unroll
        for (int i = 0; i < 4; ++i)
          Cp[(rbase + i) * N + c] = f2bf(fmaxf(acc[mt][nt][i] + bv, 0.f));
      } else {
        float* Cp = (float*)Cout;
#pragma unroll
        for (int i = 0; i < 4; ++i)
          Cp[(rbase + i) * N + c] = acc[mt][nt][i] + bv;
      }
    }
  }
}

__global__ __launch_bounds__(256) void combine_kernel(
    const float* __restrict__ y, const int* __restrict__ pair_slot,
    const float* __restrict__ out_w, float* __restrict__ out)
{
  const int gid = blockIdx.x * 256 + threadIdx.x;
  if (gid >= TOKENS * (D_MODEL / 4)) return;
  const int t = gid >> 8;
  const int qd = gid & 255;
  const float w0 = out_w[t * 2 + 0], w1 = out_w[t * 2 + 1];
  const int p0 = pair_slot[t * 2 + 0], p1 = pair_slot[t * 2 + 1];
  const float4 a = *(const float4*)(y + (size_t)p0 * D_MODEL + qd * 4);
  const float4 b = *(const float4*)(y + (size_t)p1 * D_MODEL + qd * 4);
  float4 o;
  o.x = w0 * a.x + w1 * b.x;
  o.y = w0 * a.y + w1 * b.y;
  o.z = w0 * a.z + w1 * b.z;
  o.w = w0 * a.w + w1 * b.w;
  *(float4*)(out + (size_t)t * D_MODEL + qd * 4) = o;
}

extern "C" void kernel_launch(void* const* d_in, const int* in_sizes, int n_in,
                              void* d_out, int out_size, void* d_ws, size_t ws_size,
                              hipStream_t stream)
{
  (void)in_sizes; (void)n_in; (void)out_size; (void)ws_size;
  const float* x  = (const float*)d_in[0];
  const float* gw = (const float*)d_in[1];
  const float* w1 = (const float*)d_in[2];
  const float* b1 = (const float*)d_in[3];
  const float* w2 = (const float*)d_in[4];
  const float* b2 = (const float*)d_in[5];

  float* out        = (float*)d_out;
  float* out_logits = out + (size_t)TOKENS * D_MODEL;
  float* out_idx    = out_logits + (size_t)TOKENS * NEXP;
  float* out_w      = out_idx + (size_t)TOKENS * 2;

  int* wsI       = (int*)d_ws;
  int* po        = wsI + 16;
  int* tok_list  = wsI + 512;
  int* pair_slot = wsI + 10240;
  unsigned short* xg  = (unsigned short*)((char*)d_ws + (1 << 17));
  unsigned short* w1t = xg  + (size_t)SLOTSP * D_MODEL;
  unsigned short* w2t = w1t + (size_t)NEXP * D_FF * D_MODEL;
  unsigned short* h   = w2t + (size_t)NEXP * D_MODEL * D_FF;
  float*          y   = (float*)(h + (size_t)SLOTSP * D_FF);

  init_kernel<<<SLOTSP / 256, 256, 0, stream>>>(wsI, tok_list);
  router_kernel<<<TOKENS, 256, 0, stream>>>(x, gw, out_logits, out_idx, out_w, wsI);
  offsets_kernel<<<1, 64, 0, stream>>>(wsI);
  scatter_kernel<<<SLOTS / 256, 256, 0, stream>>>(out_idx, wsI + 8, po, pair_slot, tok_list);
  gather_cvt<<<SLOTSP * 128 / 256, 256, 0, stream>>>(x, tok_list, xg);
  transpose_cvt<<<dim3(D_FF / 64, D_MODEL / 64, NEXP), 256, 0, stream>>>(w1, w1t, D_MODEL, D_FF);
  transpose_cvt<<<dim3(D_MODEL / 64, D_FF / 64, NEXP), 256, 0, stream>>>(w2, w2t, D_FF, D_MODEL);
  gemm_mfma<1><<<dim3(D_FF / 128, 72, 1), 256, 0, stream>>>(
      xg, w1t, b1, (void*)h, wsI, D_MODEL, D_FF);
  gemm_mfma<0><<<dim3(D_MODEL / 128, 72, 1), 256, 0, stream>>>(
      h, w2t, b2, (void*)y, wsI, D_FF, D_MODEL);
  combine_kernel<<<(TOKENS * D_MODEL / 4) / 256, 256, 0, stream>>>(
      y, pair_slot, out_w, out);
}

// Round 4
// 660.940 us; speedup vs baseline: 3.8007x; 1.1390x over previous
//
#include <hip/hip_runtime.h>
#include <cstdint>
#include <cstddef>

// MoE layer, MI355X. Round 4: BK=64 K-loop (half the barriers per MFMA),
// XOR-swizzled LDS (conflict-free), ballot-aggregated atomics, wave-per-token
// router. T=4096, D=1024, F=4096, E=8, top-2. Padded slots: 9216.

#define D_MODEL 1024
#define D_FF    4096
#define NEXP    8
#define TOKENS  4096
#define SLOTS   8192
#define SLOTSP  9216

typedef __bf16 bf16x8 __attribute__((ext_vector_type(8)));
typedef float  f32x4  __attribute__((ext_vector_type(4)));

static __device__ __forceinline__ unsigned short f2bf(float f) {
  unsigned int u = __float_as_uint(f);
  u += 0x7fffu + ((u >> 16) & 1u);   // RNE
  return (unsigned short)(u >> 16);
}

static __device__ __forceinline__ void async_ld16(const void* g, void* l) {
  __builtin_amdgcn_global_load_lds(
      (const __attribute__((address_space(1))) void*)g,
      (__attribute__((address_space(3))) void*)l, 16, 0, 0);
}

// ---------------- setup kernels ----------------

__global__ void init_kernel(int* __restrict__ tok_list) {
  const int g = blockIdx.x * 256 + threadIdx.x;
  if (g < SLOTSP) tok_list[g] = -1;
}

// one wave per token; no atomics
__global__ __launch_bounds__(256) void router_kernel(
    const float* __restrict__ x, const float* __restrict__ gw,
    float* __restrict__ out_logits, float* __restrict__ out_idx,
    float* __restrict__ out_w)
{
  const int w = threadIdx.x >> 6, lane = threadIdx.x & 63;
  const int t = blockIdx.x * 4 + w;
  float p[NEXP];
#pragma unroll
  for (int e = 0; e < NEXP; ++e) p[e] = 0.f;
  const float* xr = x + (size_t)t * D_MODEL;
#pragma unroll 4
  for (int i = 0; i < D_MODEL / 64; ++i) {
    const int d = i * 64 + lane;
    const float xv = xr[d];
    const float* g = gw + (size_t)d * NEXP;
#pragma unroll
    for (int e = 0; e < NEXP; ++e) p[e] += xv * g[e];
  }
#pragma unroll
  for (int e = 0; e < NEXP; ++e) {
#pragma unroll
    for (int s = 1; s < 64; s <<= 1) p[e] += __shfl_xor(p[e], s, 64);
  }
  if (lane == 0) {
    int i0 = 0;
#pragma unroll
    for (int e = 1; e < NEXP; ++e) if (p[e] > p[i0]) i0 = e;
    int i1 = (i0 == 0) ? 1 : 0;
#pragma unroll
    for (int e = 0; e < NEXP; ++e)
      if (e != i0 && p[e] > p[i1]) i1 = e;
    const float w0 = 1.f / (1.f + __expf(p[i1] - p[i0]));
#pragma unroll
    for (int e = 0; e < NEXP; ++e) out_logits[(size_t)t * NEXP + e] = p[e];
    out_idx[t * 2 + 0] = (float)i0;
    out_idx[t * 2 + 1] = (float)i1;
    out_w[t * 2 + 0] = w0;
    out_w[t * 2 + 1] = 1.f - w0;
  }
}

// single block: histogram + padded offsets + block map + zero cursors
// wsI: [8..16)=cursor [16..25)=po [25]=nb [32..104)=blk_e [128..200)=blk_gr0
__global__ __launch_bounds__(256) void count_offsets_kernel(
    const float* __restrict__ out_idx, int* __restrict__ wsI)
{
  __shared__ int hist[NEXP];
  const int tid = threadIdx.x;
  if (tid < NEXP) hist[tid] = 0;
  if (tid < NEXP) wsI[8 + tid] = 0;   // cursors
  __syncthreads();
  int c[NEXP];
#pragma unroll
  for (int e = 0; e < NEXP; ++e) c[e] = 0;
  for (int p = tid * 32; p < tid * 32 + 32; ++p) c[(int)out_idx[p]]++;
#pragma unroll
  for (int e = 0; e < NEXP; ++e) if (c[e]) atomicAdd(&hist[e], c[e]);
  __syncthreads();
  if (tid == 0) {
    int s = 0, nb = 0;
    for (int e = 0; e < NEXP; ++e) {
      wsI[16 + e] = s;
      const int nblk = (hist[e] + 127) >> 7;
      for (int j = 0; j < nblk; ++j) {
        wsI[32 + nb] = e;
        wsI[128 + nb] = s + j * 128;
        ++nb;
      }
      s += nblk << 7;
    }
    wsI[16 + NEXP] = s;
    wsI[25] = nb;
  }
}

// ballot-aggregated per-wave atomics (~8 per wave instead of 64)
__global__ void scatter_kernel(const float* __restrict__ out_idx,
                               int* __restrict__ cursor,
                               const int* __restrict__ po,
                               int* __restrict__ pair_slot,
                               int* __restrict__ tok_list)
{
  const int p = blockIdx.x * 256 + threadIdx.x;
  const int lane = threadIdx.x & 63;
  const int e = (int)out_idx[p];
  int pos = 0;
#pragma unroll
  for (int e8 = 0; e8 < NEXP; ++e8) {
    const unsigned long long m = __ballot(e == e8);
    if (m) {
      const int leader = __ffsll((long long)m) - 1;
      int base = 0;
      if (lane == leader) base = atomicAdd(&cursor[e8], (int)__popcll(m));
      base = __shfl(base, leader, 64);
      if (e == e8)
        pos = po[e8] + base +
              (int)__popcll(m & ((1ull << lane) - 1ull));
    }
  }
  tok_list[pos] = p >> 1;
  pair_slot[p] = pos;
}

// gather x rows into slot order, f32 -> bf16
__global__ __launch_bounds__(256) void gather_cvt(
    const float* __restrict__ x, const int* __restrict__ tok_list,
    unsigned short* __restrict__ xg)
{
  const int gid = blockIdx.x * 256 + threadIdx.x;
  const int row = gid >> 7, seg = gid & 127;
  const int tok = tok_list[row];
  if (tok < 0) return;
  const float* src = x + (size_t)tok * D_MODEL + seg * 8;
  const float4 a = *(const float4*)(src);
  const float4 b = *(const float4*)(src + 4);
  ushort4 lo = make_ushort4(f2bf(a.x), f2bf(a.y), f2bf(a.z), f2bf(a.w));
  ushort4 hi = make_ushort4(f2bf(b.x), f2bf(b.y), f2bf(b.z), f2bf(b.w));
  unsigned short* d = xg + (size_t)row * D_MODEL + seg * 8;
  *(ushort4*)(d) = lo;
  *(ushort4*)(d + 4) = hi;
}

// src [E][K][N] f32 -> dst [E][N][K] bf16, 64x64 LDS-tiled
__global__ __launch_bounds__(256) void transpose_cvt(
    const float* __restrict__ src, unsigned short* __restrict__ dst,
    int K, int N)
{
  const int e = blockIdx.z;
  const int n0 = blockIdx.x * 64;
  const int k0 = blockIdx.y * 64;
  __shared__ float t[64][65];
  const int c4 = (threadIdx.x & 15) * 4;
  const int r  = threadIdx.x >> 4;
  const float* s = src + (size_t)e * K * N + (size_t)k0 * N + n0;
#pragma unroll
  for (int i = 0; i < 4; ++i) {
    const float4 v = *(const float4*)(s + (size_t)(r + 16 * i) * N + c4);
    t[r + 16 * i][c4 + 0] = v.x;
    t[r + 16 * i][c4 + 1] = v.y;
    t[r + 16 * i][c4 + 2] = v.z;
    t[r + 16 * i][c4 + 3] = v.w;
  }
  __syncthreads();
  unsigned short* d = dst + (size_t)e * N * K + (size_t)n0 * K + k0;
#pragma unroll
  for (int i = 0; i < 4; ++i) {
    const int n = r + 16 * i;
    ushort4 v;
    v.x = f2bf(t[c4 + 0][n]);
    v.y = f2bf(t[c4 + 1][n]);
    v.z = f2bf(t[c4 + 2][n]);
    v.w = f2bf(t[c4 + 3][n]);
    *(ushort4*)(d + (size_t)n * K + c4) = v;
  }
}

// ---------------- MFMA grouped GEMM, BK=64 ----------------
// LDS layout: 128 rows x 8 segs(16B); data seg s of row r lives at slot s^(r&7).
// Staging: thread tid, chunk j: linear slot (j*256+tid) -> row=(..)>>3, s_lds=(..)&7,
// s_glob = s_lds ^ (row&7): 8 lanes per row fetch a permutation of the row's 128B.
// Fragment: seg = ks2*4+q -> slot = (q ^ (m15&7)) ^ (ks2*4); phases are 2-way = free.
template <int RELU>
__global__ __launch_bounds__(256) void gemm_mfma(
    const unsigned short* __restrict__ A, const unsigned short* __restrict__ Bt,
    const float* __restrict__ bias, void* __restrict__ Cout,
    const int* __restrict__ wsI, int K, int N)
{
  if ((int)blockIdx.y >= wsI[25]) return;
  const int e = wsI[32 + blockIdx.y];
  const int gr0 = wsI[128 + blockIdx.y];
  const int col0 = blockIdx.x * 128;

  __shared__ unsigned short ldsA[128 * 64];
  __shared__ unsigned short ldsB[128 * 64];

  const int tid = threadIdx.x;
  const int lane = tid & 63;
  const int w = tid >> 6;
  const int wr = w >> 1, wc = w & 1;
  const int m15 = lane & 15, q = lane >> 4;

  f32x4 zero = {0.f, 0.f, 0.f, 0.f};
  f32x4 acc[4][4];
#pragma unroll
  for (int mt = 0; mt < 4; ++mt)
#pragma unroll
    for (int nt = 0; nt < 4; ++nt) acc[mt][nt] = zero;

  // staging offsets (halfs): row0 = tid>>3, sg = (tid&7)^((tid>>3)&7)
  const size_t off0 = (size_t)(tid >> 3) * K + ((tid & 7) ^ ((tid >> 3) & 7)) * 8;
  const size_t jstep = (size_t)32 * K;
  const unsigned short* Abase = A + (size_t)gr0 * K;
  const unsigned short* Bbase = Bt + (size_t)e * N * K + (size_t)col0 * K;

  const int sw = q ^ (m15 & 7);   // fragment slot base

  for (int kk = 0; kk < K; kk += 64) {
#pragma unroll
    for (int j = 0; j < 4; ++j)
      async_ld16(Abase + off0 + j * jstep + kk, &ldsA[(j * 256 + tid) * 8]);
#pragma unroll
    for (int j = 0; j < 4; ++j)
      async_ld16(Bbase + off0 + j * jstep + kk, &ldsB[(j * 256 + tid) * 8]);
    __syncthreads();
#pragma unroll
    for (int ks2 = 0; ks2 < 2; ++ks2) {
      const int slot8 = (sw ^ (ks2 << 2)) * 8;
      bf16x8 af[4], bf[4];
#pragma unroll
      for (int mt = 0; mt < 4; ++mt)
        af[mt] = *(const bf16x8*)&ldsA[(wr * 64 + mt * 16 + m15) * 64 + slot8];
#pragma unroll
      for (int nt = 0; nt < 4; ++nt)
        bf[nt] = *(const bf16x8*)&ldsB[(wc * 64 + nt * 16 + m15) * 64 + slot8];
#pragma unroll
      for (int mt = 0; mt < 4; ++mt)
#pragma unroll
        for (int nt = 0; nt < 4; ++nt)
          acc[mt][nt] = __builtin_amdgcn_mfma_f32_16x16x32_bf16(
              af[mt], bf[nt], acc[mt][nt], 0, 0, 0);
    }
    __syncthreads();
  }

  // epilogue: C/D layout col=lane&15, row=q*4+i
#pragma unroll
  for (int nt = 0; nt < 4; ++nt) {
    const int c = col0 + wc * 64 + nt * 16 + m15;
    const float bv = bias[(size_t)e * N + c];
#pragma unroll
    for (int mt = 0; mt < 4; ++mt) {
      const size_t rbase = (size_t)(gr0 + wr * 64 + mt * 16 + q * 4);
      if (RELU) {
        unsigned short* Cp = (unsigned short*)Cout;
#pragma unroll
        for (int i = 0; i < 4; ++i)
          Cp[(rbase + i) * N + c] = f2bf(fmaxf(acc[mt][nt][i] + bv, 0.f));
      } else {
        float* Cp = (float*)Cout;
#pragma unroll
        for (int i = 0; i < 4; ++i)
          Cp[(rbase + i) * N + c] = acc[mt][nt][i] + bv;
      }
    }
  }
}

__global__ __launch_bounds__(256) void combine_kernel(
    const float* __restrict__ y, const int* __restrict__ pair_slot,
    const float* __restrict__ out_w, float* __restrict__ out)
{
  const int gid = blockIdx.x * 256 + threadIdx.x;
  if (gid >= TOKENS * (D_MODEL / 4)) return;
  const int t = gid >> 8;
  const int qd = gid & 255;
  const float w0 = out_w[t * 2 + 0], w1 = out_w[t * 2 + 1];
  const int p0 = pair_slot[t * 2 + 0], p1 = pair_slot[t * 2 + 1];
  const float4 a = *(const float4*)(y + (size_t)p0 * D_MODEL + qd * 4);
  const float4 b = *(const float4*)(y + (size_t)p1 * D_MODEL + qd * 4);
  float4 o;
  o.x = w0 * a.x + w1 * b.x;
  o.y = w0 * a.y + w1 * b.y;
  o.z = w0 * a.z + w1 * b.z;
  o.w = w0 * a.w + w1 * b.w;
  *(float4*)(out + (size_t)t * D_MODEL + qd * 4) = o;
}

extern "C" void kernel_launch(void* const* d_in, const int* in_sizes, int n_in,
                              void* d_out, int out_size, void* d_ws, size_t ws_size,
                              hipStream_t stream)
{
  (void)in_sizes; (void)n_in; (void)out_size; (void)ws_size;
  const float* x  = (const float*)d_in[0];
  const float* gw = (const float*)d_in[1];
  const float* w1 = (const float*)d_in[2];
  const float* b1 = (const float*)d_in[3];
  const float* w2 = (const float*)d_in[4];
  const float* b2 = (const float*)d_in[5];

  float* out        = (float*)d_out;
  float* out_logits = out + (size_t)TOKENS * D_MODEL;
  float* out_idx    = out_logits + (size_t)TOKENS * NEXP;
  float* out_w      = out_idx + (size_t)TOKENS * 2;

  int* wsI       = (int*)d_ws;
  int* po        = wsI + 16;
  int* tok_list  = wsI + 512;
  int* pair_slot = wsI + 10240;
  unsigned short* xg  = (unsigned short*)((char*)d_ws + (1 << 17));
  unsigned short* w1t = xg  + (size_t)SLOTSP * D_MODEL;
  unsigned short* w2t = w1t + (size_t)NEXP * D_FF * D_MODEL;
  unsigned short* h   = w2t + (size_t)NEXP * D_MODEL * D_FF;
  float*          y   = (float*)(h + (size_t)SLOTSP * D_FF);

  init_kernel<<<SLOTSP / 256, 256, 0, stream>>>(tok_list);
  router_kernel<<<TOKENS / 4, 256, 0, stream>>>(x, gw, out_logits, out_idx, out_w);
  count_offsets_kernel<<<1, 256, 0, stream>>>(out_idx, wsI);
  scatter_kernel<<<SLOTS / 256, 256, 0, stream>>>(out_idx, wsI + 8, po, pair_slot, tok_list);
  gather_cvt<<<SLOTSP * 128 / 256, 256, 0, stream>>>(x, tok_list, xg);
  transpose_cvt<<<dim3(D_FF / 64, D_MODEL / 64, NEXP), 256, 0, stream>>>(w1, w1t, D_MODEL, D_FF);
  transpose_cvt<<<dim3(D_MODEL / 64, D_FF / 64, NEXP), 256, 0, stream>>>(w2, w2t, D_FF, D_MODEL);
  gemm_mfma<1><<<dim3(D_FF / 128, 72, 1), 256, 0, stream>>>(
      xg, w1t, b1, (void*)h, wsI, D_MODEL, D_FF);
  gemm_mfma<0><<<dim3(D_MODEL / 128, 72, 1), 256, 0, stream>>>(
      h, w2t, b2, (void*)y, wsI, D_FF, D_MODEL);
  combine_kernel<<<(TOKENS * D_MODEL / 4) / 256, 256, 0, stream>>>(
      y, pair_slot, out_w, out);
}